// Round 8
// baseline (480.335 us; speedup 1.0000x reference)
//
#include <hip/hip_runtime.h>
#include <hip/hip_bf16.h>
#include <stdint.h>

#define D_HID 256

typedef float v4f __attribute__((ext_vector_type(4)));
typedef short v8s __attribute__((ext_vector_type(8)));

static __device__ __forceinline__ unsigned short f2bf(float f) {
    union { float f; uint32_t u; } a; a.f = f;
    uint32_t u = a.u;
    uint32_t r = (u + 0x7FFFu + ((u >> 16) & 1u)) >> 16;   // round-nearest-even
    return (unsigned short)r;
}
static __device__ __forceinline__ float bf2f(unsigned short u) {
    union { uint32_t u; float f; } a; a.u = ((uint32_t)u) << 16;
    return a.f;
}

// ---------------- degree count ----------------
__global__ void deg_kernel(const int* __restrict__ dst, int* __restrict__ degi, int E) {
    int e = blockIdx.x * blockDim.x + threadIdx.x;
    if (e < E) atomicAdd(&degi[dst[e]], 1);
}

__global__ void dinv_kernel(const int* __restrict__ degi, float* __restrict__ dinv, int N) {
    int n = blockIdx.x * blockDim.x + threadIdx.x;
    if (n < N) dinv[n] = rsqrtf((float)degi[n] + 1.0f);
}

// ---------------- exclusive scan ----------------
__global__ __launch_bounds__(256) void scanA(const int* __restrict__ degi,
                                             int* __restrict__ row_off,
                                             int* __restrict__ partials, int N) {
    __shared__ int sdata[256];
    int tid = threadIdx.x;
    int base = blockIdx.x * 1024 + tid * 4;
    int s[4];
#pragma unroll
    for (int j = 0; j < 4; ++j) s[j] = (base + j < N) ? degi[base + j] : 0;
    int t = s[0] + s[1] + s[2] + s[3];
    sdata[tid] = t;
    __syncthreads();
    for (int ofs = 1; ofs < 256; ofs <<= 1) {
        int v = (tid >= ofs) ? sdata[tid - ofs] : 0;
        __syncthreads();
        sdata[tid] += v;
        __syncthreads();
    }
    int excl = sdata[tid] - t;
    int run = excl;
#pragma unroll
    for (int j = 0; j < 4; ++j) {
        if (base + j < N) row_off[base + j] = run;
        run += s[j];
    }
    if (tid == 255) partials[blockIdx.x] = sdata[255];
}

__global__ __launch_bounds__(128) void scanB(int* __restrict__ partials, int nb) {
    __shared__ int s[128];
    int tid = threadIdx.x;
    int v = (tid < nb) ? partials[tid] : 0;
    s[tid] = v;
    __syncthreads();
    for (int ofs = 1; ofs < 128; ofs <<= 1) {
        int t = (tid >= ofs) ? s[tid - ofs] : 0;
        __syncthreads();
        s[tid] += t;
        __syncthreads();
    }
    if (tid < nb) partials[tid] = s[tid] - v;   // exclusive
}

__global__ __launch_bounds__(256) void scanC(int* __restrict__ row_off,
                                             const int* __restrict__ partials, int N) {
    int add = partials[blockIdx.x];
    int base = blockIdx.x * 1024 + threadIdx.x * 4;
#pragma unroll
    for (int j = 0; j < 4; ++j)
        if (base + j < N) row_off[base + j] += add;
}

// ---------------- CSR fill ----------------
__global__ void fill_kernel(const int* __restrict__ src, const int* __restrict__ dst,
                            const int* __restrict__ row_off, int* __restrict__ cursor,
                            const float* __restrict__ dinv, int2* __restrict__ csr, int E) {
    int e = blockIdx.x * blockDim.x + threadIdx.x;
    if (e >= E) return;
    int s = src[e], t = dst[e];
    int pos = row_off[t] + atomicAdd(&cursor[t], 1);
    csr[pos] = make_int2(s, __float_as_int(dinv[s] * dinv[t]));
}

// ---------------- weight transpose + bf16 cast for all 3 layers ----------------
// Wt[l][n][k] = bf16(W_l[k][n]);  grid = 3*256 blocks of 16x16
__global__ __launch_bounds__(256) void transpose_cast3(const float* __restrict__ W0,
                                                       const float* __restrict__ W1,
                                                       const float* __restrict__ W2,
                                                       unsigned short* __restrict__ Wt) {
    __shared__ float t[16][17];
    int l = blockIdx.x >> 8;
    int bi = blockIdx.x & 255;
    const float* W = (l == 0) ? W0 : (l == 1) ? W1 : W2;
    int bx = bi & 15, by = bi >> 4;
    int tx = threadIdx.x & 15, ty = threadIdx.x >> 4;
    t[ty][tx] = W[(by * 16 + ty) * 256 + bx * 16 + tx];
    __syncthreads();
    Wt[(size_t)l * 65536 + (size_t)(bx * 16 + ty) * 256 + by * 16 + tx] = f2bf(t[tx][ty]);
}

// ---------------- embedding: hb = bf16(x @ W_emb + b_emb)  (K=10) ----------------
__global__ __launch_bounds__(256) void emb_kernel(const float* __restrict__ x,
                                                  const float* __restrict__ W,
                                                  const float* __restrict__ b,
                                                  unsigned short* __restrict__ hb, int N) {
    int wave = threadIdx.x >> 6;
    int lane = threadIdx.x & 63;
    int n = blockIdx.x * 4 + wave;
    if (n >= N) return;
    float xv = (lane < 10) ? x[n * 10 + lane] : 0.f;
    float s0 = b[lane * 4 + 0], s1 = b[lane * 4 + 1], s2 = b[lane * 4 + 2], s3 = b[lane * 4 + 3];
#pragma unroll
    for (int k = 0; k < 10; ++k) {
        float xk = __shfl(xv, k);
        s0 += xk * W[k * D_HID + lane * 4 + 0];
        s1 += xk * W[k * D_HID + lane * 4 + 1];
        s2 += xk * W[k * D_HID + lane * 4 + 2];
        s3 += xk * W[k * D_HID + lane * 4 + 3];
    }
    size_t i4 = (size_t)n * D_HID + lane * 4;
    ushort4 o; o.x = f2bf(s0); o.y = f2bf(s1); o.z = f2bf(s2); o.w = f2bf(s3);
    *(ushort4*)&hb[i4] = o;
}

// ---------------- LDS-free streaming bf16 MFMA GEMM ----------------
// One wave owns a 32x256 output strip. A-frags from global (L1-resident strip),
// B-frags from global (L2-broadcast: every wave reads the same 128 KB Wt).
#define SROWS 32
__global__ __launch_bounds__(256) void gemm_bf16_v3(const unsigned short* __restrict__ hb,
                                                    const unsigned short* __restrict__ Wt,
                                                    unsigned short* __restrict__ hwb, int M) {
    int wid = (blockIdx.x * 256 + threadIdx.x) >> 6;   // global wave id = strip id
    int lane = threadIdx.x & 63;
    int row0 = wid * SROWS;
    if (row0 >= M) return;
    int fr = lane & 15;            // row within 16-row fragment
    int fc = (lane >> 4) * 8;      // k offset within 32

    v4f acc0[16] = {};             // rows row0..row0+15, n-tiles 0..15
    v4f acc1[16] = {};             // rows row0+16..row0+31

    int ar0 = row0 + fr;           // guarded: M % 32 == 0 in this harness, but clamp anyway
    int ar1 = row0 + 16 + fr;
    if (ar0 > M - 1) ar0 = M - 1;
    if (ar1 > M - 1) ar1 = M - 1;
    const unsigned short* A0 = hb + (size_t)ar0 * 256 + fc;
    const unsigned short* A1 = hb + (size_t)ar1 * 256 + fc;
    const unsigned short* Bp = Wt + (size_t)fr * 256 + fc;

#pragma unroll
    for (int k = 0; k < 8; ++k) {
        v8s a0 = *(const v8s*)(A0 + k * 32);
        v8s a1 = *(const v8s*)(A1 + k * 32);
#pragma unroll
        for (int n = 0; n < 16; ++n) {
            v8s b = *(const v8s*)(Bp + (size_t)n * 16 * 256 + k * 32);
            acc0[n] = __builtin_amdgcn_mfma_f32_16x16x32_bf16(a0, b, acc0[n], 0, 0, 0);
            acc1[n] = __builtin_amdgcn_mfma_f32_16x16x32_bf16(a1, b, acc1[n], 0, 0, 0);
        }
    }

    int cr = (lane >> 4) * 4;      // C row group within 16
    int cc = lane & 15;            // C col within 16
#pragma unroll
    for (int n = 0; n < 16; ++n) {
#pragma unroll
        for (int q = 0; q < 4; ++q) {
            int r0 = row0 + cr + q;
            int r1 = row0 + 16 + cr + q;
            if (r0 < M) hwb[(size_t)r0 * 256 + n * 16 + cc] = f2bf(acc0[n][q]);
            if (r1 < M) hwb[(size_t)r1 * 256 + n * 16 + cc] = f2bf(acc1[n][q]);
        }
    }
}

// ---------------- fused gather-aggregate + combine (all-bf16 residual stream) ----------------
__global__ __launch_bounds__(256) void agg_combine(const int* __restrict__ row_off,
                                                   const int* __restrict__ degi,
                                                   const int2* __restrict__ csr,
                                                   const unsigned short* __restrict__ hwb,
                                                   const float* __restrict__ dinv,
                                                   const float* __restrict__ b,
                                                   unsigned short* __restrict__ hb,
                                                   float* __restrict__ out,
                                                   int N, int last) {
    int wave = threadIdx.x >> 6;
    int lane = threadIdx.x & 63;
    int n = blockIdx.x * 4 + wave;
    if (n >= N) return;
    int off = row_off[n];
    int d = degi[n];
    float4 acc = make_float4(0.f, 0.f, 0.f, 0.f);
    int i = 0;
    for (; i + 2 <= d; i += 2) {
        int2 p0 = csr[off + i];
        int2 p1 = csr[off + i + 1];
        float n0 = __int_as_float(p0.y);
        float n1 = __int_as_float(p1.y);
        ushort4 r0 = *(const ushort4*)&hwb[(size_t)p0.x * D_HID + lane * 4];
        ushort4 r1 = *(const ushort4*)&hwb[(size_t)p1.x * D_HID + lane * 4];
        acc.x += bf2f(r0.x) * n0 + bf2f(r1.x) * n1;
        acc.y += bf2f(r0.y) * n0 + bf2f(r1.y) * n1;
        acc.z += bf2f(r0.z) * n0 + bf2f(r1.z) * n1;
        acc.w += bf2f(r0.w) * n0 + bf2f(r1.w) * n1;
    }
    if (i < d) {
        int2 p0 = csr[off + i];
        float n0 = __int_as_float(p0.y);
        ushort4 r0 = *(const ushort4*)&hwb[(size_t)p0.x * D_HID + lane * 4];
        acc.x += bf2f(r0.x) * n0;
        acc.y += bf2f(r0.y) * n0;
        acc.z += bf2f(r0.z) * n0;
        acc.w += bf2f(r0.w) * n0;
    }
    float di = dinv[n];
    float sl = di * di;
    size_t i4 = (size_t)n * D_HID + lane * 4;
    ushort4 wv4 = *(const ushort4*)&hwb[i4];
    ushort4 hv4 = *(const ushort4*)&hb[i4];
    float4 bb = *(const float4*)&b[lane * 4];
    float4 r;
    r.x = fmaxf(acc.x + bf2f(wv4.x) * sl + bb.x, 0.f) + bf2f(hv4.x);
    r.y = fmaxf(acc.y + bf2f(wv4.y) * sl + bb.y, 0.f) + bf2f(hv4.y);
    r.z = fmaxf(acc.z + bf2f(wv4.z) * sl + bb.z, 0.f) + bf2f(hv4.z);
    r.w = fmaxf(acc.w + bf2f(wv4.w) * sl + bb.w, 0.f) + bf2f(hv4.w);
    if (last) {
        *(float4*)&out[i4] = r;
    } else {
        ushort4 o;
        o.x = f2bf(r.x); o.y = f2bf(r.y); o.z = f2bf(r.z); o.w = f2bf(r.w);
        *(ushort4*)&hb[i4] = o;
    }
}

extern "C" void kernel_launch(void* const* d_in, const int* in_sizes, int n_in,
                              void* d_out, int out_size, void* d_ws, size_t ws_size,
                              hipStream_t stream) {
    const float* x     = (const float*)d_in[0];
    const int*   edge  = (const int*)d_in[1];
    const float* W_emb = (const float*)d_in[2];
    const float* b_emb = (const float*)d_in[3];
    const float* W[3]  = {(const float*)d_in[4], (const float*)d_in[6], (const float*)d_in[8]};
    const float* B[3]  = {(const float*)d_in[5], (const float*)d_in[7], (const float*)d_in[9]};

    int N = in_sizes[0] / 10;       // 100000
    int E = in_sizes[1] / 2;        // 320000
    size_t NH = (size_t)N * D_HID;

    float* out = (float*)d_out;
    unsigned short* hwb = (unsigned short*)d_ws;        // NH bf16
    unsigned short* hb  = hwb + NH;                     // NH bf16
    unsigned short* Wt  = hb + NH;                      // 3*65536 bf16
    int2*  csr = (int2*)(Wt + 3 * 65536);               // E
    int*   degi     = (int*)(csr + E);
    float* dinv     = (float*)(degi + N);
    int*   row_off  = (int*)(dinv + N);
    int*   cursor   = row_off + N;
    int*   partials = cursor + N;

    const int* src = edge;
    const int* dst = edge + E;

    int nb = (N + 1023) / 1024;     // 98

    // ---- CSR build (layer-invariant) ----
    hipMemsetAsync(degi, 0, (size_t)N * sizeof(int), stream);
    deg_kernel<<<(E + 255) / 256, 256, 0, stream>>>(dst, degi, E);
    dinv_kernel<<<(N + 255) / 256, 256, 0, stream>>>(degi, dinv, N);
    scanA<<<nb, 256, 0, stream>>>(degi, row_off, partials, N);
    scanB<<<1, 128, 0, stream>>>(partials, nb);
    scanC<<<nb, 256, 0, stream>>>(row_off, partials, N);
    hipMemsetAsync(cursor, 0, (size_t)N * sizeof(int), stream);
    fill_kernel<<<(E + 255) / 256, 256, 0, stream>>>(src, dst, row_off, cursor, dinv, csr, E);

    // ---- weights -> bf16 transposed (single fused launch) ----
    transpose_cast3<<<3 * 256, 256, 0, stream>>>(W[0], W[1], W[2], Wt);

    // ---- embedding ----
    emb_kernel<<<(N + 3) / 4, 256, 0, stream>>>(x, W_emb, b_emb, hb, N);

    // ---- 3 GCN layers ----
    int nwaves = (N + SROWS - 1) / SROWS;               // 3125
    int gblocks = (nwaves * 64 + 255) / 256;            // 782
    for (int l = 0; l < 3; ++l) {
        gemm_bf16_v3<<<gblocks, 256, 0, stream>>>(hb, Wt + (size_t)l * 65536, hwb, N);
        agg_combine<<<(N + 3) / 4, 256, 0, stream>>>(row_off, degi, csr, hwb, dinv, B[l],
                                                     hb, out, N, l == 2 ? 1 : 0);
    }
}